// Round 4
// baseline (323.837 us; speedup 1.0000x reference)
//
#include <hip/hip_runtime.h>
#include <stdint.h>

// Problem constants: B=32, S=2048, K=512, V=512, H=256
#define Bb 32
#define Ss 2048
#define Kk 512
#define Vv 512
#define Hh 256

#define OUTP (Bb * Vv) // offset of p within d_out (out [1,B,V] then p [B,S])

// ws layout (bytes):
//   [0,       32768)   hq[B][H] fp32 (= q@Wq^T + bq + bk)
//   [32768,  294912)   Wk bf16, frag-major: [stage128][grp=kk*4+lg][h][8]
//   [294912, 557056)   logits[B][S] fp32
#define WS_HQ 0
#define WS_WKB 32768
#define WS_LOGIT 294912

typedef float floatx4 __attribute__((ext_vector_type(4)));
typedef __bf16 bf16x8 __attribute__((ext_vector_type(8)));

__device__ __forceinline__ uint32_t bfround(float f) {
  uint32_t u = __float_as_uint(f);
  return (u + 0x7fffu + ((u >> 16) & 1u)) >> 16;
}
__device__ __forceinline__ uint32_t packbf(float lo, float hi) {
  return bfround(lo) | (bfround(hi) << 16);
}

// ---------------------------------------------------------------------------
// prep (merged): blocks [0,128): retile Wk fp32 -> bf16 frag-major (BK=128).
//                blocks [128,384): hq[b][h] = q[b]·Wq[h] + bq[h] + bk[h]
__global__ void prep(const float* __restrict__ q, const float* __restrict__ Wq,
                     const float* __restrict__ bq, const float* __restrict__ bk,
                     const float* __restrict__ Wk, uint16_t* __restrict__ wkb,
                     float* __restrict__ hq) {
  __shared__ float red[256];
  const int bx = blockIdx.x;
  const int t = threadIdx.x;
  if (bx < 128) {
    const int i = (bx * 256 + t) * 4; // 4 consecutive k of one h row
    float4 w = *(const float4*)(Wk + i);
    const int h = i >> 9;
    const int k = i & 511;
    const int stage = k >> 7;  // 4 stages of K=128
    const int kin = k & 127;
    const int grp = kin >> 3;  // kk*4+lg (0..15)
    const int j = kin & 7;     // 0 or 4 here
    uint2 pk;
    pk.x = packbf(w.x, w.y);
    pk.y = packbf(w.z, w.w);
    *(uint2*)(wkb + stage * 32768 + (grp * 256 + h) * 8 + j) = pk;
  } else {
    const int idx = bx - 128; // 0..255
    const int b = idx >> 3;
    const int hc = idx & 7;
    const int h_in = t & 31;
    const int kp = t >> 5; // 8-way K split
    const int h = hc * 32 + h_in;
    const float4* qp = (const float4*)(q + b * Kk + kp * 64);
    const float4* wp = (const float4*)(Wq + h * Kk + kp * 64);
    float acc = 0.f;
#pragma unroll
    for (int i = 0; i < 16; ++i) {
      float4 qa = qp[i], wa = wp[i];
      acc = fmaf(qa.x, wa.x, acc);
      acc = fmaf(qa.y, wa.y, acc);
      acc = fmaf(qa.z, wa.z, acc);
      acc = fmaf(qa.w, wa.w, acc);
    }
    red[t] = acc;
    __syncthreads();
    if (t < 32) {
      float s = 0.f;
#pragma unroll
      for (int kp2 = 0; kp2 < 8; ++kp2) s += red[kp2 * 32 + t];
      const int hh = hc * 32 + t;
      hq[b * Hh + hh] = s + bq[hh] + bk[hh];
    }
  }
}

// ---------------------------------------------------------------------------
// Main GEMM+tanh+logit. BM=64 rows of k, BN=256 (full H), BK=128, 4 stages.
//   - 3 in-loop __syncthreads total (vs 7): each vmcnt(0) drain is preceded by
//     ~520cy of MFMA, so the next-stage A prefetch (HBM ~900cy) is mostly
//     covered and the per-stage exposed latency shrinks ~3x.
//   - B (Wk, L2-hot) single-buffered in registers, loaded per-stage at stage
//     top; compiler's exact vmcnt(N) lets kk-group 0 start after its own 4
//     frags arrive. No LDS for B.
//   - A staged via coalesced fp32 loads (32 lanes = one row's 512B) -> cvt ->
//     ds_write, LDS double-buffered (2 x 16 KB).
__global__ __launch_bounds__(256, 2) void fused_gemm_tanh_logit(
    const float* __restrict__ kin, const uint16_t* __restrict__ wkb,
    const float* __restrict__ hq, const float* __restrict__ Wo,
    float* __restrict__ logits) {
  __shared__ __align__(16) uint16_t lA[2][64 * 128]; // [buf][((kk*4+lg)*64+m)*8+j]
  __shared__ float lpart[4][64];

  const int tid = threadIdx.x;
  const int b = blockIdx.y;
  const int s0 = blockIdx.x * 64;
  const int wid = tid >> 6;
  const int lane = tid & 63;
  const int l15 = lane & 15;
  const int lg = lane >> 4;

  float hqv[4], wov[4];
#pragma unroll
  for (int ni = 0; ni < 4; ++ni) {
    const int n = wid * 64 + ni * 16 + l15;
    hqv[ni] = hq[b * Hh + n];
    wov[ni] = Wo[n];
  }

  floatx4 acc[4][4];
#pragma unroll
  for (int mi = 0; mi < 4; ++mi)
#pragma unroll
    for (int ni = 0; ni < 4; ++ni) acc[mi][ni] = (floatx4){0.f, 0.f, 0.f, 0.f};

  // ---- A staging geometry: 32 lanes cover one row's 512B contiguous chunk
  const int r0 = tid >> 5; // base row 0..7; rows r0+8c, c=0..7
  const int j = tid & 31;  // float4 index within the 128-float stage chunk
  const size_t CROW8 = (size_t)8 * Bb * Kk; // 8-row stride in floats
  const float* aptr = kin + ((size_t)(s0 + r0) * Bb + b) * Kk + j * 4;
  // frag-major LDS write: elem kin=j*4+q -> grp=j>>1, sub=(j&1)*4+q
  uint16_t* wbase = &lA[0][0] + (((j >> 1) * 64 + r0) * 8 + (j & 1) * 4);

  // ---- B (frag-major in ws): frag (ks,kk,ni) at uint16 offset
  //      ks*32768 + kk*8192 + ni*128 from bptr
  const uint16_t* bptr = wkb + ((size_t)lg * 256 + wid * 64 + l15) * 8;

  float4 av[8];

  // ---------------- prologue: issue A0 and A1 back-to-back ----------------
  {
    float4 a0[8];
#pragma unroll
    for (int c = 0; c < 8; ++c) a0[c] = *(const float4*)(aptr + c * CROW8);
#pragma unroll
    for (int c = 0; c < 8; ++c) av[c] = *(const float4*)(aptr + c * CROW8 + 128);
#pragma unroll
    for (int c = 0; c < 8; ++c) {
      uint2 pk;
      pk.x = packbf(a0[c].x, a0[c].y);
      pk.y = packbf(a0[c].z, a0[c].w);
      *(uint2*)(wbase + c * 64) = pk;
    }
  }
  __syncthreads();

  // ---------------- 4-stage pipeline, 3 in-loop barriers ----------------
#pragma unroll
  for (int ks = 0; ks < 4; ++ks) {
    const int cur = ks & 1, nxt = cur ^ 1;
    // 1. B frags for THIS stage (L2-hot; exact vmcnt lets kk=0 start early)
    bf16x8 breg[16];
#pragma unroll
    for (int kk = 0; kk < 4; ++kk)
#pragma unroll
      for (int ni = 0; ni < 4; ++ni)
        breg[kk * 4 + ni] =
            *(const bf16x8*)(bptr + (size_t)ks * 32768 + kk * 8192 + ni * 128);
    // 2. A cvt+write for stage ks+1 into the other LDS buffer
    if (ks < 3) {
#pragma unroll
      for (int c = 0; c < 8; ++c) {
        uint2 pk;
        pk.x = packbf(av[c].x, av[c].y);
        pk.y = packbf(av[c].z, av[c].w);
        *(uint2*)(wbase + nxt * 8192 + c * 64) = pk;
      }
    }
    // 3. A global prefetch for stage ks+2 (drained at this stage's barrier,
    //    ~520cy of MFMA below covers most of the HBM latency)
    if (ks < 2) {
#pragma unroll
      for (int c = 0; c < 8; ++c)
        av[c] = *(const float4*)(aptr + c * CROW8 + (ks + 2) * 128);
    }
    // 4. compute stage ks: 4 kk-groups x 16 MFMA
#pragma unroll
    for (int kk = 0; kk < 4; ++kk) {
      bf16x8 af[4];
#pragma unroll
      for (int mi = 0; mi < 4; ++mi)
        af[mi] = *(const bf16x8*)&lA[cur][((kk * 4 + lg) * 64 + mi * 16 + l15) * 8];
#pragma unroll
      for (int mi = 0; mi < 4; ++mi)
#pragma unroll
        for (int ni = 0; ni < 4; ++ni)
          acc[mi][ni] = __builtin_amdgcn_mfma_f32_16x16x32_bf16(
              af[mi], breg[kk * 4 + ni], acc[mi][ni], 0, 0, 0);
    }
    // 5. stage barrier
    if (ks < 3) __syncthreads();
  }

  // epilogue: tanh + dot with Wo; C/D layout: col = lane&15, row = lg*4 + reg
#pragma unroll
  for (int mi = 0; mi < 4; ++mi) {
#pragma unroll
    for (int r = 0; r < 4; ++r) {
      float sum = 0.f;
#pragma unroll
      for (int ni = 0; ni < 4; ++ni) {
        const float x = acc[mi][ni][r] + hqv[ni];
        const float e = __expf(2.f * x);
        const float th = 1.f - 2.f * __builtin_amdgcn_rcpf(e + 1.f);
        sum = fmaf(th, wov[ni], sum);
      }
      sum += __shfl_xor(sum, 1, 64);
      sum += __shfl_xor(sum, 2, 64);
      sum += __shfl_xor(sum, 4, 64);
      sum += __shfl_xor(sum, 8, 64);
      if (l15 == 0) lpart[wid][mi * 16 + lg * 4 + r] = sum;
    }
  }
  __syncthreads();
  if (tid < 64) {
    const float lv = lpart[0][tid] + lpart[1][tid] + lpart[2][tid] + lpart[3][tid];
    logits[b * Ss + s0 + tid] = lv; // bo omitted: cancels in softmax
  }
}

// ---------------------------------------------------------------------------
// softmax over S per b -> p into d_out; zero out-section for vsum atomics.
__global__ void softmax_zero(const float* __restrict__ logits, float* __restrict__ dout) {
  const int b = blockIdx.x;
  const int t = threadIdx.x; // 256
  const int wid = t >> 6, lane = t & 63;
  __shared__ float red[4];
  const float4* lp = (const float4*)(logits + b * Ss);
  const float4 x0 = lp[t * 2], x1 = lp[t * 2 + 1];
  float mx = fmaxf(fmaxf(fmaxf(x0.x, x0.y), fmaxf(x0.z, x0.w)),
                   fmaxf(fmaxf(x1.x, x1.y), fmaxf(x1.z, x1.w)));
#pragma unroll
  for (int off = 1; off < 64; off <<= 1) mx = fmaxf(mx, __shfl_xor(mx, off, 64));
  if (lane == 0) red[wid] = mx;
  __syncthreads();
  mx = fmaxf(fmaxf(red[0], red[1]), fmaxf(red[2], red[3]));
  __syncthreads();
  float e[8];
  e[0] = __expf(x0.x - mx); e[1] = __expf(x0.y - mx);
  e[2] = __expf(x0.z - mx); e[3] = __expf(x0.w - mx);
  e[4] = __expf(x1.x - mx); e[5] = __expf(x1.y - mx);
  e[6] = __expf(x1.z - mx); e[7] = __expf(x1.w - mx);
  float s = ((e[0] + e[1]) + (e[2] + e[3])) + ((e[4] + e[5]) + (e[6] + e[7]));
#pragma unroll
  for (int off = 1; off < 64; off <<= 1) s += __shfl_xor(s, off, 64);
  if (lane == 0) red[wid] = s;
  __syncthreads();
  s = (red[0] + red[1]) + (red[2] + red[3]);
  const float inv = 1.f / s;
  float4 p0, p1;
  p0.x = e[0] * inv; p0.y = e[1] * inv; p0.z = e[2] * inv; p0.w = e[3] * inv;
  p1.x = e[4] * inv; p1.y = e[5] * inv; p1.z = e[6] * inv; p1.w = e[7] * inv;
  float4* pout = (float4*)(dout + OUTP + b * Ss);
  pout[t * 2] = p0;
  pout[t * 2 + 1] = p1;
  dout[b * Vv + t] = 0.f;
  dout[b * Vv + 256 + t] = 0.f;
}

// ---------------------------------------------------------------------------
// out[b][:] += sum_s p[b][s] * v[s][b][:].  float4 coalesced streaming of v.
__global__ __launch_bounds__(256) void weighted_vsum(const float* __restrict__ v,
                                                     float* __restrict__ dout) {
  const int sc = blockIdx.x; // 16 S-chunks of 128
  const int b = blockIdx.y;  // 32
  const int t = threadIdx.x;
  __shared__ float lp[128];
  if (t < 128) lp[t] = dout[OUTP + b * Ss + sc * 128 + t];
  __syncthreads();
  const int c4 = t & 127; // float4 column
  const int sh = t >> 7;  // 0/1: s parity
  float4 acc = {0.f, 0.f, 0.f, 0.f};
#pragma unroll 8
  for (int i = 0; i < 64; ++i) {
    const int sl = sh + 2 * i;
    const int s = sc * 128 + sl;
    const float4 vv = *(const float4*)(v + ((size_t)s * Bb + b) * Vv + c4 * 4);
    const float pw = lp[sl];
    acc.x = fmaf(pw, vv.x, acc.x);
    acc.y = fmaf(pw, vv.y, acc.y);
    acc.z = fmaf(pw, vv.z, acc.z);
    acc.w = fmaf(pw, vv.w, acc.w);
  }
  float* o = dout + b * Vv + c4 * 4;
  atomicAdd(o + 0, acc.x);
  atomicAdd(o + 1, acc.y);
  atomicAdd(o + 2, acc.z);
  atomicAdd(o + 3, acc.w);
}

// ---------------------------------------------------------------------------
extern "C" void kernel_launch(void* const* d_in, const int* in_sizes, int n_in,
                              void* d_out, int out_size, void* d_ws, size_t ws_size,
                              hipStream_t stream) {
  const float* q  = (const float*)d_in[0];
  const float* k  = (const float*)d_in[1];
  const float* v  = (const float*)d_in[2];
  const float* Wk = (const float*)d_in[3];
  const float* bk = (const float*)d_in[4];
  const float* Wq = (const float*)d_in[5];
  const float* bq = (const float*)d_in[6];
  const float* Wo = (const float*)d_in[7];

  float* out = (float*)d_out;
  char* ws = (char*)d_ws;
  float* hq = (float*)(ws + WS_HQ);
  uint16_t* wkb = (uint16_t*)(ws + WS_WKB);
  float* logits = (float*)(ws + WS_LOGIT);

  prep<<<dim3(384), dim3(256), 0, stream>>>(q, Wq, bq, bk, Wk, wkb, hq);
  fused_gemm_tanh_logit<<<dim3(Ss / 64, Bb), dim3(256), 0, stream>>>(k, wkb, hq, Wo, logits);
  softmax_zero<<<dim3(Bb), dim3(256), 0, stream>>>(logits, out);
  weighted_vsum<<<dim3(16, Bb), dim3(256), 0, stream>>>(v, out);
}

// Round 5
// 312.698 us; speedup vs baseline: 1.0356x; 1.0356x over previous
//
#include <hip/hip_runtime.h>
#include <stdint.h>

// Problem constants: B=32, S=2048, K=512, V=512, H=256
#define Bb 32
#define Ss 2048
#define Kk 512
#define Vv 512
#define Hh 256

#define OUTP (Bb * Vv) // offset of p within d_out (out [1,B,V] then p [B,S])

// ws layout (bytes):
//   [0,       32768)   hq[B][H] fp32 (= q@Wq^T + bq + bk)
//   [32768,  294912)   Wk bf16, frag-major: [stage32][grp=lg][h][8]
//   [294912, 557056)   logits[B][S] fp32
#define WS_HQ 0
#define WS_WKB 32768
#define WS_LOGIT 294912

typedef float floatx4 __attribute__((ext_vector_type(4)));
typedef __bf16 bf16x8 __attribute__((ext_vector_type(8)));

__device__ __forceinline__ uint32_t bfround(float f) {
  uint32_t u = __float_as_uint(f);
  return (u + 0x7fffu + ((u >> 16) & 1u)) >> 16;
}
__device__ __forceinline__ uint32_t packbf(float lo, float hi) {
  return bfround(lo) | (bfround(hi) << 16);
}

// async global->LDS, 16B per lane; lds dest is wave-uniform base + lane*16
__device__ __forceinline__ void gload_lds16(const uint16_t* g, uint16_t* l) {
  __builtin_amdgcn_global_load_lds((const __attribute__((address_space(1))) void*)g,
                                   (__attribute__((address_space(3))) void*)l, 16, 0, 0);
}

// ---------------------------------------------------------------------------
// prep (merged): blocks [0,128): retile Wk fp32 -> bf16 frag-major (BK=32).
//                blocks [128,384): hq[b][h] = q[b]·Wq[h] + bq[h] + bk[h]
__global__ void prep(const float* __restrict__ q, const float* __restrict__ Wq,
                     const float* __restrict__ bq, const float* __restrict__ bk,
                     const float* __restrict__ Wk, uint16_t* __restrict__ wkb,
                     float* __restrict__ hq) {
  __shared__ float red[256];
  const int bx = blockIdx.x;
  const int t = threadIdx.x;
  if (bx < 128) {
    const int i = (bx * 256 + t) * 4; // 4 consecutive k of one h row
    float4 w = *(const float4*)(Wk + i);
    const int h = i >> 9;
    const int k = i & 511;
    const int stage = k >> 5;      // 16 stages of K=32
    const int grp = (k & 31) >> 3; // lg group 0..3
    const int j = k & 7;           // 0 or 4 here
    uint2 pk;
    pk.x = packbf(w.x, w.y);
    pk.y = packbf(w.z, w.w);
    *(uint2*)(wkb + stage * 8192 + (grp * 256 + h) * 8 + j) = pk;
  } else {
    const int idx = bx - 128; // 0..255
    const int b = idx >> 3;
    const int hc = idx & 7;
    const int h_in = t & 31;
    const int kp = t >> 5; // 8-way K split
    const int h = hc * 32 + h_in;
    const float4* qp = (const float4*)(q + b * Kk + kp * 64);
    const float4* wp = (const float4*)(Wq + h * Kk + kp * 64);
    float acc = 0.f;
#pragma unroll
    for (int i = 0; i < 16; ++i) {
      float4 qa = qp[i], wa = wp[i];
      acc = fmaf(qa.x, wa.x, acc);
      acc = fmaf(qa.y, wa.y, acc);
      acc = fmaf(qa.z, wa.z, acc);
      acc = fmaf(qa.w, wa.w, acc);
    }
    red[t] = acc;
    __syncthreads();
    if (t < 32) {
      float s = 0.f;
#pragma unroll
      for (int kp2 = 0; kp2 < 8; ++kp2) s += red[kp2 * 32 + t];
      const int hh = hc * 32 + t;
      hq[b * Hh + hh] = s + bq[hh] + bk[hh];
    }
  }
}

// ---------------------------------------------------------------------------
// Main GEMM+tanh+logit over linearized rows r = s*32+b (k is row-major
// [65536][512], so each block's 64-row A tile is one contiguous 128KB arena).
// BM=64 rows, BN=256 (full H), BK=32, 16 stages.
//   - B (Wk frags) via global_load_lds (0 VGPR), double-buffered: issued for
//     stage ks+1 during stage ks; the __syncthreads vmcnt drain comes a full
//     compute phase after issue.
//   - A: coalesced contiguous fp32 loads -> cvt -> single uint4 ds_write,
//     LDS double-buffered; global prefetch 2 stages ahead.
//   - LDS 40960 B -> 4 blocks/CU; VGPR ~115 with launch_bounds(256,4)
//     -> up to 16 waves/CU (vs 8 in R3/R4). lpart overlays dead lA.
__global__ __launch_bounds__(256, 4) void fused_gemm_tanh_logit(
    const float* __restrict__ kin, const uint16_t* __restrict__ wkb,
    const float* __restrict__ hq, const float* __restrict__ Wo,
    float* __restrict__ logits) {
  __shared__ __align__(16) uint16_t lA[2][2048]; // [buf][(grp*64+row)*8+j]
  __shared__ __align__(16) uint16_t lB[2][8192]; // [buf][(grp*256+n)*8+j]

  const int tid = threadIdx.x;
  const int r0 = blockIdx.x * 64; // first linear row
  const int wid = tid >> 6;
  const int lane = tid & 63;
  const int l15 = lane & 15;
  const int lg = lane >> 4;

  float wov[4];
#pragma unroll
  for (int ni = 0; ni < 4; ++ni) wov[ni] = Wo[wid * 64 + ni * 16 + l15];

  floatx4 acc[4][4];
#pragma unroll
  for (int mi = 0; mi < 4; ++mi)
#pragma unroll
    for (int ni = 0; ni < 4; ++ni) acc[mi][ni] = (floatx4){0.f, 0.f, 0.f, 0.f};

  // ---- A staging: thread t covers 8 floats of row (t>>2), part (t&3)
  const int arow = tid >> 2;
  const int apart = tid & 3;
  const float* aptr = kin + (size_t)(r0 + arow) * Kk + apart * 8;
  // frag-major LDS slot: grp == apart, contiguous uint4 per thread
  uint16_t* awr = &lA[0][0] + (apart * 64 + arow) * 8;

  // ---- B staging (linear copy; wkb layout == lB layout)
  const uint16_t* bsrc = wkb + (wid * 4) * 512 + lane * 8;
  uint16_t* bdst = &lB[0][0] + (wid * 4) * 512;

  float4 av0, av1;

  // ---------------- prologue ----------------
#pragma unroll
  for (int it = 0; it < 4; ++it) gload_lds16(bsrc + it * 512, bdst + it * 512);
  {
    float4 a0 = *(const float4*)(aptr);
    float4 a1 = *(const float4*)(aptr + 4);
    av0 = *(const float4*)(aptr + 32);
    av1 = *(const float4*)(aptr + 36);
    uint4 w;
    w.x = packbf(a0.x, a0.y);
    w.y = packbf(a0.z, a0.w);
    w.z = packbf(a1.x, a1.y);
    w.w = packbf(a1.z, a1.w);
    *(uint4*)awr = w;
  }
  __syncthreads();

  // ---------------- 16-stage pipeline ----------------
#pragma unroll
  for (int ks = 0; ks < 16; ++ks) {
    const int cur = ks & 1, nxt = cur ^ 1;
    // 1. B for stage ks+1 (async, 0 VGPR; drained at this stage's barrier,
    //    one full compute phase after issue)
    if (ks < 15) {
#pragma unroll
      for (int it = 0; it < 4; ++it)
        gload_lds16(bsrc + (ks + 1) * 8192 + it * 512, bdst + nxt * 8192 + it * 512);
    }
    // 2. A cvt+write for stage ks+1
    if (ks < 15) {
      uint4 w;
      w.x = packbf(av0.x, av0.y);
      w.y = packbf(av0.z, av0.w);
      w.z = packbf(av1.x, av1.y);
      w.w = packbf(av1.z, av1.w);
      *(uint4*)(awr + nxt * 2048) = w;
    }
    // 3. A global prefetch for stage ks+2
    if (ks < 14) {
      av0 = *(const float4*)(aptr + (ks + 2) * 32);
      av1 = *(const float4*)(aptr + (ks + 2) * 32 + 4);
    }
    // 4. compute stage ks: 16 MFMA
    {
      bf16x8 af[4], bfr[4];
#pragma unroll
      for (int mi = 0; mi < 4; ++mi)
        af[mi] = *(const bf16x8*)&lA[cur][(lg * 64 + mi * 16 + l15) * 8];
#pragma unroll
      for (int ni = 0; ni < 4; ++ni)
        bfr[ni] = *(const bf16x8*)&lB[cur][(lg * 256 + wid * 64 + ni * 16 + l15) * 8];
#pragma unroll
      for (int mi = 0; mi < 4; ++mi)
#pragma unroll
        for (int ni = 0; ni < 4; ++ni)
          acc[mi][ni] = __builtin_amdgcn_mfma_f32_16x16x32_bf16(
              af[mi], bfr[ni], acc[mi][ni], 0, 0, 0);
    }
    // 5. stage barrier
    if (ks < 15) __syncthreads();
  }

  // epilogue: tanh + dot with Wo. C row = mi*16 + lg*4 + r; its batch
  // b = (mi&1)*16 + lg*4 + r (row&31). Process mi-parity halves to cap VGPR.
  float* lpart = (float*)&lA[0][0]; // overlay: lA dead after last barrier+reads
#pragma unroll
  for (int pp = 0; pp < 2; ++pp) {
    float hqv[4][4];
#pragma unroll
    for (int r = 0; r < 4; ++r)
#pragma unroll
      for (int ni = 0; ni < 4; ++ni)
        hqv[r][ni] = hq[(pp * 16 + lg * 4 + r) * Hh + wid * 64 + ni * 16 + l15];
#pragma unroll
    for (int mm = 0; mm < 2; ++mm) {
      const int mi = pp + mm * 2;
#pragma unroll
      for (int r = 0; r < 4; ++r) {
        float sum = 0.f;
#pragma unroll
        for (int ni = 0; ni < 4; ++ni) {
          const float x = acc[mi][ni][r] + hqv[r][ni];
          const float e = __expf(2.f * x);
          const float th = 1.f - 2.f * __builtin_amdgcn_rcpf(e + 1.f);
          sum = fmaf(th, wov[ni], sum);
        }
        sum += __shfl_xor(sum, 1, 64);
        sum += __shfl_xor(sum, 2, 64);
        sum += __shfl_xor(sum, 4, 64);
        sum += __shfl_xor(sum, 8, 64);
        if (l15 == 0) lpart[wid * 64 + mi * 16 + lg * 4 + r] = sum;
      }
    }
  }
  __syncthreads();
  if (tid < 64) {
    const float lv = lpart[0 * 64 + tid] + lpart[1 * 64 + tid] +
                     lpart[2 * 64 + tid] + lpart[3 * 64 + tid];
    // row r = r0 + tid -> b = tid&31, s = (r0>>5) + (tid>>5)
    logits[(tid & 31) * Ss + (r0 >> 5) + (tid >> 5)] = lv; // bo cancels in softmax
  }
}

// ---------------------------------------------------------------------------
// softmax over S per b -> p into d_out; zero out-section for vsum atomics.
__global__ void softmax_zero(const float* __restrict__ logits, float* __restrict__ dout) {
  const int b = blockIdx.x;
  const int t = threadIdx.x; // 256
  const int wid = t >> 6, lane = t & 63;
  __shared__ float red[4];
  const float4* lp = (const float4*)(logits + b * Ss);
  const float4 x0 = lp[t * 2], x1 = lp[t * 2 + 1];
  float mx = fmaxf(fmaxf(fmaxf(x0.x, x0.y), fmaxf(x0.z, x0.w)),
                   fmaxf(fmaxf(x1.x, x1.y), fmaxf(x1.z, x1.w)));
#pragma unroll
  for (int off = 1; off < 64; off <<= 1) mx = fmaxf(mx, __shfl_xor(mx, off, 64));
  if (lane == 0) red[wid] = mx;
  __syncthreads();
  mx = fmaxf(fmaxf(red[0], red[1]), fmaxf(red[2], red[3]));
  __syncthreads();
  float e[8];
  e[0] = __expf(x0.x - mx); e[1] = __expf(x0.y - mx);
  e[2] = __expf(x0.z - mx); e[3] = __expf(x0.w - mx);
  e[4] = __expf(x1.x - mx); e[5] = __expf(x1.y - mx);
  e[6] = __expf(x1.z - mx); e[7] = __expf(x1.w - mx);
  float s = ((e[0] + e[1]) + (e[2] + e[3])) + ((e[4] + e[5]) + (e[6] + e[7]));
#pragma unroll
  for (int off = 1; off < 64; off <<= 1) s += __shfl_xor(s, off, 64);
  if (lane == 0) red[wid] = s;
  __syncthreads();
  s = (red[0] + red[1]) + (red[2] + red[3]);
  const float inv = 1.f / s;
  float4 p0, p1;
  p0.x = e[0] * inv; p0.y = e[1] * inv; p0.z = e[2] * inv; p0.w = e[3] * inv;
  p1.x = e[4] * inv; p1.y = e[5] * inv; p1.z = e[6] * inv; p1.w = e[7] * inv;
  float4* pout = (float4*)(dout + OUTP + b * Ss);
  pout[t * 2] = p0;
  pout[t * 2 + 1] = p1;
  dout[b * Vv + t] = 0.f;
  dout[b * Vv + 256 + t] = 0.f;
}

// ---------------------------------------------------------------------------
// out[b][:] += sum_s p[b][s] * v[s][b][:].  float4 coalesced streaming of v.
__global__ __launch_bounds__(256) void weighted_vsum(const float* __restrict__ v,
                                                     float* __restrict__ dout) {
  const int sc = blockIdx.x; // 16 S-chunks of 128
  const int b = blockIdx.y;  // 32
  const int t = threadIdx.x;
  __shared__ float lp[128];
  if (t < 128) lp[t] = dout[OUTP + b * Ss + sc * 128 + t];
  __syncthreads();
  const int c4 = t & 127; // float4 column
  const int sh = t >> 7;  // 0/1: s parity
  float4 acc = {0.f, 0.f, 0.f, 0.f};
#pragma unroll 8
  for (int i = 0; i < 64; ++i) {
    const int sl = sh + 2 * i;
    const int s = sc * 128 + sl;
    const float4 vv = *(const float4*)(v + ((size_t)s * Bb + b) * Vv + c4 * 4);
    const float pw = lp[sl];
    acc.x = fmaf(pw, vv.x, acc.x);
    acc.y = fmaf(pw, vv.y, acc.y);
    acc.z = fmaf(pw, vv.z, acc.z);
    acc.w = fmaf(pw, vv.w, acc.w);
  }
  float* o = dout + b * Vv + c4 * 4;
  atomicAdd(o + 0, acc.x);
  atomicAdd(o + 1, acc.y);
  atomicAdd(o + 2, acc.z);
  atomicAdd(o + 3, acc.w);
}

// ---------------------------------------------------------------------------
extern "C" void kernel_launch(void* const* d_in, const int* in_sizes, int n_in,
                              void* d_out, int out_size, void* d_ws, size_t ws_size,
                              hipStream_t stream) {
  const float* q  = (const float*)d_in[0];
  const float* k  = (const float*)d_in[1];
  const float* v  = (const float*)d_in[2];
  const float* Wk = (const float*)d_in[3];
  const float* bk = (const float*)d_in[4];
  const float* Wq = (const float*)d_in[5];
  const float* bq = (const float*)d_in[6];
  const float* Wo = (const float*)d_in[7];

  float* out = (float*)d_out;
  char* ws = (char*)d_ws;
  float* hq = (float*)(ws + WS_HQ);
  uint16_t* wkb = (uint16_t*)(ws + WS_WKB);
  float* logits = (float*)(ws + WS_LOGIT);

  prep<<<dim3(384), dim3(256), 0, stream>>>(q, Wq, bq, bk, Wk, wkb, hq);
  fused_gemm_tanh_logit<<<dim3((Ss * Bb) / 64), dim3(256), 0, stream>>>(k, wkb, hq, Wo, logits);
  softmax_zero<<<dim3(Bb), dim3(256), 0, stream>>>(logits, out);
  weighted_vsum<<<dim3(16, Bb), dim3(256), 0, stream>>>(v, out);
}

// Round 6
// 299.662 us; speedup vs baseline: 1.0807x; 1.0435x over previous
//
#include <hip/hip_runtime.h>
#include <stdint.h>

// Problem constants: B=32, S=2048, K=512, V=512, H=256
#define Bb 32
#define Ss 2048
#define Kk 512
#define Vv 512
#define Hh 256

#define OUTP (Bb * Vv) // offset of p within d_out (out [1,B,V] then p [B,S])

// ws layout (bytes):
//   [0,       32768)   hq[B][H] fp32 (= q@Wq^T + bq + bk)
//   [32768,  294912)   Wk bf16, frag-major: [stage32][grp=lg][h][8]
//   [294912, 557056)   w[B][S] fp32 (unnormalized exp(logit))
#define WS_HQ 0
#define WS_WKB 32768
#define WS_LOGIT 294912

typedef float floatx4 __attribute__((ext_vector_type(4)));
typedef __bf16 bf16x8 __attribute__((ext_vector_type(8)));

__device__ __forceinline__ uint32_t bfround(float f) {
  uint32_t u = __float_as_uint(f);
  return (u + 0x7fffu + ((u >> 16) & 1u)) >> 16;
}
__device__ __forceinline__ uint32_t packbf(float lo, float hi) {
  return bfround(lo) | (bfround(hi) << 16);
}

// async global->LDS, 16B per lane; lds dest is wave-uniform base + lane*16
__device__ __forceinline__ void gload_lds16(const uint16_t* g, uint16_t* l) {
  __builtin_amdgcn_global_load_lds((const __attribute__((address_space(1))) void*)g,
                                   (__attribute__((address_space(3))) void*)l, 16, 0, 0);
}

// ---------------------------------------------------------------------------
// prep (merged): blocks [0,128): retile Wk fp32 -> bf16 frag-major (BK=32).
//                blocks [128,384): hq[b][h] = q[b]·Wq[h] + bq[h] + bk[h]
//                block 384: zero the out-section of d_out (gemm atomics land there)
__global__ void prep(const float* __restrict__ q, const float* __restrict__ Wq,
                     const float* __restrict__ bq, const float* __restrict__ bk,
                     const float* __restrict__ Wk, uint16_t* __restrict__ wkb,
                     float* __restrict__ hq, float* __restrict__ dout) {
  __shared__ float red[256];
  const int bx = blockIdx.x;
  const int t = threadIdx.x;
  if (bx < 128) {
    const int i = (bx * 256 + t) * 4; // 4 consecutive k of one h row
    float4 w = *(const float4*)(Wk + i);
    const int h = i >> 9;
    const int k = i & 511;
    const int stage = k >> 5;      // 16 stages of K=32
    const int grp = (k & 31) >> 3; // lg group 0..3
    const int j = k & 7;           // 0 or 4 here
    uint2 pk;
    pk.x = packbf(w.x, w.y);
    pk.y = packbf(w.z, w.w);
    *(uint2*)(wkb + stage * 8192 + (grp * 256 + h) * 8 + j) = pk;
  } else if (bx < 384) {
    const int idx = bx - 128; // 0..255
    const int b = idx >> 3;
    const int hc = idx & 7;
    const int h_in = t & 31;
    const int kp = t >> 5; // 8-way K split
    const int h = hc * 32 + h_in;
    const float4* qp = (const float4*)(q + b * Kk + kp * 64);
    const float4* wp = (const float4*)(Wq + h * Kk + kp * 64);
    float acc = 0.f;
#pragma unroll
    for (int i = 0; i < 16; ++i) {
      float4 qa = qp[i], wa = wp[i];
      acc = fmaf(qa.x, wa.x, acc);
      acc = fmaf(qa.y, wa.y, acc);
      acc = fmaf(qa.z, wa.z, acc);
      acc = fmaf(qa.w, wa.w, acc);
    }
    red[t] = acc;
    __syncthreads();
    if (t < 32) {
      float s = 0.f;
#pragma unroll
      for (int kp2 = 0; kp2 < 8; ++kp2) s += red[kp2 * 32 + t];
      const int hh = hc * 32 + t;
      hq[b * Hh + hh] = s + bq[hh] + bk[hh];
    }
  } else {
    // zero out-section: Bb*Vv = 16384 floats = 4096 float4
    float4 z = {0.f, 0.f, 0.f, 0.f};
    float4* o = (float4*)dout + t;
#pragma unroll
    for (int i = 0; i < 16; ++i) o[i * 256] = z;
  }
}

// ---------------------------------------------------------------------------
// Main GEMM+tanh+logit+exp + fused weighted-V accumulation.
// Block (sc, b): 64 consecutive s for one batch b. BM=64, BN=256, BK=32,
// 16 stages (R5's proven pipeline core):
//   - B via global_load_lds (0 VGPR), double-buffered, issued 1 stage ahead.
//   - A coalesced fp32 loads (4 threads cover one row's 128B stage chunk)
//     -> cvt -> uint4 ds_write, double-buffered; global prefetch 2 ahead.
//   - Epilogue: tanh + Wo-dot -> logit -> w = exp(logit) (no max subtraction:
//     |logit| <= 25.6, fp32-safe); store w; then accumulate sum_s w*v[s,b,:]
//     into dout via atomics (v read once globally, in gemm's shadow).
//   - LDS 40960 B -> 4 blocks/CU; lpart/sw overlay dead lA[0].
__global__ __launch_bounds__(256, 4) void fused_gemm_tanh_logit(
    const float* __restrict__ kin, const uint16_t* __restrict__ wkb,
    const float* __restrict__ hq, const float* __restrict__ Wo,
    float* __restrict__ wlog, const float* __restrict__ vin,
    float* __restrict__ dout) {
  __shared__ __align__(16) uint16_t lA[2][2048]; // [buf][(grp*64+row)*8+j]
  __shared__ __align__(16) uint16_t lB[2][8192]; // [buf][(grp*256+n)*8+j]

  const int tid = threadIdx.x;
  const int sc = blockIdx.x; // s-chunk (64 rows)
  const int b = blockIdx.y;
  const int wid = tid >> 6;
  const int lane = tid & 63;
  const int l15 = lane & 15;
  const int lg = lane >> 4;

  float hqv[4], wov[4];
#pragma unroll
  for (int ni = 0; ni < 4; ++ni) {
    const int n = wid * 64 + ni * 16 + l15;
    hqv[ni] = hq[b * Hh + n];
    wov[ni] = Wo[n];
  }

  floatx4 acc[4][4];
#pragma unroll
  for (int mi = 0; mi < 4; ++mi)
#pragma unroll
    for (int ni = 0; ni < 4; ++ni) acc[mi][ni] = (floatx4){0.f, 0.f, 0.f, 0.f};

  // ---- A staging: thread t covers 8 floats of row (t>>2), part (t&3)
  const int arow = tid >> 2; // s-offset 0..63
  const int apart = tid & 3;
  const float* aptr = kin + ((size_t)((sc * 64 + arow) * Bb) + b) * Kk + apart * 8;
  uint16_t* awr = &lA[0][0] + (apart * 64 + arow) * 8;

  // ---- B staging (linear copy; wkb layout == lB layout)
  const uint16_t* bsrc = wkb + (wid * 4) * 512 + lane * 8;
  uint16_t* bdst = &lB[0][0] + (wid * 4) * 512;

  float4 av0, av1;

  // ---------------- prologue ----------------
#pragma unroll
  for (int it = 0; it < 4; ++it) gload_lds16(bsrc + it * 512, bdst + it * 512);
  {
    float4 a0 = *(const float4*)(aptr);
    float4 a1 = *(const float4*)(aptr + 4);
    av0 = *(const float4*)(aptr + 32);
    av1 = *(const float4*)(aptr + 36);
    uint4 w;
    w.x = packbf(a0.x, a0.y);
    w.y = packbf(a0.z, a0.w);
    w.z = packbf(a1.x, a1.y);
    w.w = packbf(a1.z, a1.w);
    *(uint4*)awr = w;
  }
  __syncthreads();

  // ---------------- 16-stage pipeline ----------------
#pragma unroll
  for (int ks = 0; ks < 16; ++ks) {
    const int cur = ks & 1, nxt = cur ^ 1;
    // 1. B for stage ks+1 (async, 0 VGPR; drained at this stage's barrier)
    if (ks < 15) {
#pragma unroll
      for (int it = 0; it < 4; ++it)
        gload_lds16(bsrc + (ks + 1) * 8192 + it * 512, bdst + nxt * 8192 + it * 512);
    }
    // 2. A cvt+write for stage ks+1
    if (ks < 15) {
      uint4 w;
      w.x = packbf(av0.x, av0.y);
      w.y = packbf(av0.z, av0.w);
      w.z = packbf(av1.x, av1.y);
      w.w = packbf(av1.z, av1.w);
      *(uint4*)(awr + nxt * 2048) = w;
    }
    // 3. A global prefetch for stage ks+2
    if (ks < 14) {
      av0 = *(const float4*)(aptr + (ks + 2) * 32);
      av1 = *(const float4*)(aptr + (ks + 2) * 32 + 4);
    }
    // 4. compute stage ks: 16 MFMA
    {
      bf16x8 af[4], bfr[4];
#pragma unroll
      for (int mi = 0; mi < 4; ++mi)
        af[mi] = *(const bf16x8*)&lA[cur][(lg * 64 + mi * 16 + l15) * 8];
#pragma unroll
      for (int ni = 0; ni < 4; ++ni)
        bfr[ni] = *(const bf16x8*)&lB[cur][(lg * 256 + wid * 64 + ni * 16 + l15) * 8];
#pragma unroll
      for (int mi = 0; mi < 4; ++mi)
#pragma unroll
        for (int ni = 0; ni < 4; ++ni)
          acc[mi][ni] = __builtin_amdgcn_mfma_f32_16x16x32_bf16(
              af[mi], bfr[ni], acc[mi][ni], 0, 0, 0);
    }
    // 5. stage barrier
    if (ks < 15) __syncthreads();
  }

  // epilogue: tanh + dot with Wo; C/D layout: col = lane&15, row = lg*4 + reg
  float* lpart = (float*)&lA[0][0];       // 256 floats, overlays dead lA[0]
  float* sw = (float*)&lA[0][0] + 256;    // 64 floats (bytes 1024..1280)
#pragma unroll
  for (int mi = 0; mi < 4; ++mi) {
#pragma unroll
    for (int r = 0; r < 4; ++r) {
      float sum = 0.f;
#pragma unroll
      for (int ni = 0; ni < 4; ++ni) {
        const float x = acc[mi][ni][r] + hqv[ni];
        const float e = __expf(2.f * x);
        const float th = 1.f - 2.f * __builtin_amdgcn_rcpf(e + 1.f);
        sum = fmaf(th, wov[ni], sum);
      }
      sum += __shfl_xor(sum, 1, 64);
      sum += __shfl_xor(sum, 2, 64);
      sum += __shfl_xor(sum, 4, 64);
      sum += __shfl_xor(sum, 8, 64);
      if (l15 == 0) lpart[wid * 64 + mi * 16 + lg * 4 + r] = sum;
    }
  }
  __syncthreads();
  if (tid < 64) {
    const float lv = lpart[tid] + lpart[64 + tid] + lpart[128 + tid] + lpart[192 + tid];
    const float w = __expf(lv); // |lv| <= 25.6 -> fp32-safe; max-sub redundant
    wlog[b * Ss + sc * 64 + tid] = w;
    sw[tid] = w;
  }
  __syncthreads();

  // fused weighted-V accumulation: out[b][:] += sum_{s in chunk} w_s * v[s][b][:]
  const int c = tid * 2; // float2 column; wave = contiguous 512B per s-row
  float ax = 0.f, ay = 0.f;
#pragma unroll 8
  for (int s = 0; s < 64; ++s) {
    const float2 vv = *(const float2*)(vin + ((size_t)((sc * 64 + s) * Bb) + b) * Vv + c);
    const float pw = sw[s];
    ax = fmaf(pw, vv.x, ax);
    ay = fmaf(pw, vv.y, ay);
  }
  float* o = dout + b * Vv + c;
  atomicAdd(o + 0, ax);
  atomicAdd(o + 1, ay);
}

// ---------------------------------------------------------------------------
// finalize: per b, D = sum_s w; p = w/D; out *= 1/D.
__global__ void finalize(const float* __restrict__ wlog, float* __restrict__ dout) {
  const int b = blockIdx.x;
  const int t = threadIdx.x; // 256
  const int wid = t >> 6, lane = t & 63;
  __shared__ float red[4];
  const float4* wp = (const float4*)(wlog + b * Ss);
  const float4 x0 = wp[t * 2], x1 = wp[t * 2 + 1];
  float s = ((x0.x + x0.y) + (x0.z + x0.w)) + ((x1.x + x1.y) + (x1.z + x1.w));
#pragma unroll
  for (int off = 1; off < 64; off <<= 1) s += __shfl_xor(s, off, 64);
  if (lane == 0) red[wid] = s;
  __syncthreads();
  s = (red[0] + red[1]) + (red[2] + red[3]);
  const float inv = 1.f / s;
  float4 p0, p1;
  p0.x = x0.x * inv; p0.y = x0.y * inv; p0.z = x0.z * inv; p0.w = x0.w * inv;
  p1.x = x1.x * inv; p1.y = x1.y * inv; p1.z = x1.z * inv; p1.w = x1.w * inv;
  float4* pout = (float4*)(dout + OUTP + b * Ss);
  pout[t * 2] = p0;
  pout[t * 2 + 1] = p1;
  // scale out-section (atomic-accumulated U) by 1/D
  float2* op = (float2*)(dout + b * Vv + t * 2);
  float2 ov = *op;
  ov.x *= inv;
  ov.y *= inv;
  *op = ov;
}

// ---------------------------------------------------------------------------
extern "C" void kernel_launch(void* const* d_in, const int* in_sizes, int n_in,
                              void* d_out, int out_size, void* d_ws, size_t ws_size,
                              hipStream_t stream) {
  const float* q  = (const float*)d_in[0];
  const float* k  = (const float*)d_in[1];
  const float* v  = (const float*)d_in[2];
  const float* Wk = (const float*)d_in[3];
  const float* bk = (const float*)d_in[4];
  const float* Wq = (const float*)d_in[5];
  const float* bq = (const float*)d_in[6];
  const float* Wo = (const float*)d_in[7];

  float* out = (float*)d_out;
  char* ws = (char*)d_ws;
  float* hq = (float*)(ws + WS_HQ);
  uint16_t* wkb = (uint16_t*)(ws + WS_WKB);
  float* wlog = (float*)(ws + WS_LOGIT);

  prep<<<dim3(385), dim3(256), 0, stream>>>(q, Wq, bq, bk, Wk, wkb, hq, out);
  fused_gemm_tanh_logit<<<dim3(Ss / 64, Bb), dim3(256), 0, stream>>>(k, wkb, hq, Wo, wlog, v, out);
  finalize<<<dim3(Bb), dim3(256), 0, stream>>>(wlog, out);
}